// Round 1
// baseline (27223.212 us; speedup 1.0000x reference)
//
#include <hip/hip_runtime.h>
#include <cstdint>
#include <cstddef>

#define B_ 64
#define S_ 512
#define D_ 1024
#define H_ 1024
#define G_ 4096       // 4*H
#define NBLK 256      // cooperative grid for recurrence

typedef short short8 __attribute__((ext_vector_type(8)));
typedef float floatx4 __attribute__((ext_vector_type(4)));

__device__ __forceinline__ unsigned short bf16_rne(float f) {
  union { float f; unsigned u; } v; v.f = f;
  return (unsigned short)((v.u + 0x7FFFu + ((v.u >> 16) & 1u)) >> 16);
}
__device__ __forceinline__ float sigf(float x) { return 1.0f / (1.0f + __expf(-x)); }
__device__ __forceinline__ float tanhf_fast(float x) {
  float e = __expf(2.0f * x);
  return 1.0f - 2.0f / (e + 1.0f);   // safe at +-inf (no NaN)
}

// ---------------- prep kernels ----------------
__global__ void f32_to_bf16_k(const float* __restrict__ s, unsigned short* __restrict__ d, int n) {
  int i = (blockIdx.x * 256 + threadIdx.x) * 4;
  if (i < n) {
    float4 v = *(const float4*)(s + i);
    ushort4 o;
    o.x = bf16_rne(v.x); o.y = bf16_rne(v.y); o.z = bf16_rne(v.z); o.w = bf16_rne(v.w);
    *(ushort4*)(d + i) = o;
  }
}

__global__ void bsum_k(const float* __restrict__ bi, const float* __restrict__ bh, float* __restrict__ o) {
  int i = blockIdx.x * 256 + threadIdx.x;
  if (i < G_) o[i] = bi[i] + bh[i];
}

__global__ void hinit_k(const float* __restrict__ h0, unsigned short* __restrict__ hb) {
  int i = blockIdx.x * 256 + threadIdx.x;   // 0..65535
  if (i < B_ * H_) hb[i] = bf16_rne(h0[i & (H_ - 1)]);
}

// ---------------- phase 1: xg = x @ Wi^T + (bi+bh) ----------------
// 128x128 tile, BK=64, 4 waves each computing 64x64 via 4x4 16x16x32 MFMAs.
__global__ __launch_bounds__(256, 3) void gemm_xg(
    const unsigned short* __restrict__ xa,   // [32768][1024] bf16 (token-major: b*512+s)
    const unsigned short* __restrict__ wb,   // [4096][1024] bf16
    const float* __restrict__ bsum,          // [4096]
    void* __restrict__ xgv, int xg16)        // out: [512][64][4096]
{
  __shared__ unsigned short As[128 * 72];    // pad 64->72 elems to break bank conflicts
  __shared__ unsigned short Bs[128 * 72];
  const int tid = threadIdx.x, ln = tid & 63, wv = tid >> 6;
  const int q = ln >> 4, lr = ln & 15;
  const int bid = blockIdx.x;
  const int nt = bid & 31, mt = bid >> 5;
  const int m0 = mt << 7, n0 = nt << 7;
  const int wm = (wv & 1) << 6, wn = (wv >> 1) << 6;
  floatx4 acc[4][4] = {};

  for (int kk = 0; kk < 1024; kk += 64) {
    __syncthreads();
#pragma unroll
    for (int i = 0; i < 4; i++) {
      int f = i * 256 + tid;                 // 1024 chunks of 8 elems
      int row = f >> 3, c8 = (f & 7) << 3;
      short8 va = *(const short8*)(xa + (size_t)(m0 + row) * 1024 + kk + c8);
      short8 vb = *(const short8*)(wb + (size_t)(n0 + row) * 1024 + kk + c8);
      *(short8*)(As + row * 72 + c8) = va;
      *(short8*)(Bs + row * 72 + c8) = vb;
    }
    __syncthreads();
#pragma unroll
    for (int ks = 0; ks < 2; ks++) {
      short8 af[4], bf[4];
#pragma unroll
      for (int mi = 0; mi < 4; mi++)
        af[mi] = *(const short8*)(As + (wm + mi * 16 + lr) * 72 + ks * 32 + q * 8);
#pragma unroll
      for (int ni = 0; ni < 4; ni++)
        bf[ni] = *(const short8*)(Bs + (wn + ni * 16 + lr) * 72 + ks * 32 + q * 8);
#pragma unroll
      for (int mi = 0; mi < 4; mi++)
#pragma unroll
        for (int ni = 0; ni < 4; ni++)
          acc[mi][ni] = __builtin_amdgcn_mfma_f32_16x16x32_bf16(af[mi], bf[ni], acc[mi][ni], 0, 0, 0);
    }
  }
  // epilogue: D row = q*4+reg, col = lr ; write xg[s][b][n]
  const int b = m0 >> 9, s0 = m0 & 511;
#pragma unroll
  for (int mi = 0; mi < 4; mi++) {
#pragma unroll
    for (int r = 0; r < 4; r++) {
      int mrow = wm + mi * 16 + q * 4 + r;
      size_t base = (size_t)(s0 + mrow) * (B_ * G_) + (size_t)b * G_;
#pragma unroll
      for (int ni = 0; ni < 4; ni++) {
        int n = n0 + wn + ni * 16 + lr;
        float v = acc[mi][ni][r] + bsum[n];
        if (xg16) ((unsigned short*)xgv)[base + n] = bf16_rne(v);
        else      ((float*)xgv)[base + n] = v;
      }
    }
  }
}

// ---------------- phase 2: persistent cooperative recurrence ----------------
// 256 blocks = 4 batch-groups x 64 col-groups. Block owns 16 batch rows x 16 h-cols.
// 16 waves: wave = (nt in 0..3 [4 h-cols each], kt in 0..3 [K chunk of 256]).
// Wh fragments live in registers for the whole kernel. c state in fp32 registers.
__global__ __launch_bounds__(1024, 4) void lstm_rec(
    const void* __restrict__ xgv, int xg16,  // [512][64][4096] (biases folded in)
    const unsigned short* __restrict__ wh,   // [4096][1024] bf16
    unsigned short* __restrict__ hb,         // [2][64][1024] bf16 (double buffer)
    const float* __restrict__ c0,            // [1024]
    float* __restrict__ out_hid,             // [64][512][1024]
    float* __restrict__ out_h,               // [64][1024]
    float* __restrict__ out_c,               // [64][1024]
    unsigned* __restrict__ cnt)
{
  __shared__ unsigned short hs[16 * 1032];   // h tile, padded rows (+8 elems)
  __shared__ float red[3][4][16][16];        // K-split partials [kt-1][nt][m][n]

  const int tid = threadIdx.x, ln = tid & 63, wv = tid >> 6;
  const int nt = wv & 3, kt = wv >> 2;
  const int bid = blockIdx.x, bg = bid & 3, cg = bid >> 2;
  const int r0 = bg << 4, j0 = cg << 4;
  const int nloc = ln & 15, q = ln >> 4;
  const int tg = nloc >> 2, u = nloc & 3;    // gate type / h-col within group
  const int j = j0 + (nt << 2) + u;          // this lane's h column
  const int gcol = tg * 1024 + j;            // this lane's Wh row (gate column)

  // load Wh fragments once: lane holds Wh[gcol][kt*256 + s8*32 + q*8 .. +8]
  short8 bfr[8];
#pragma unroll
  for (int s8 = 0; s8 < 8; s8++)
    bfr[s8] = *(const short8*)(wh + (size_t)gcol * 1024 + kt * 256 + s8 * 32 + q * 8);

  float cst[4];
#pragma unroll
  for (int r = 0; r < 4; r++) cst[r] = c0[j];  // broadcast over batch

  for (int t = 0; t < 512; t++) {
    const unsigned short* hr = hb + (t & 1) * (B_ * H_);
    unsigned short* hw = hb + ((t + 1) & 1) * (B_ * H_);

    // prefetch this step's xg values (independent of the barrier)
    float xv[4] = {0.f, 0.f, 0.f, 0.f};
    if (kt == 0) {
      const size_t xbase = (size_t)t * (B_ * G_) + (size_t)r0 * G_ + gcol;
      if (xg16) {
#pragma unroll
        for (int r = 0; r < 4; r++) {
          unsigned short w = ((const unsigned short*)xgv)[xbase + (size_t)(q * 4 + r) * G_];
          union { unsigned uu; float ff; } cv; cv.uu = ((unsigned)w) << 16; xv[r] = cv.ff;
        }
      } else {
#pragma unroll
        for (int r = 0; r < 4; r++)
          xv[r] = ((const float*)xgv)[xbase + (size_t)(q * 4 + r) * G_];
      }
    }

    // stage h tile: 16 rows x 1024 cols bf16 -> LDS (2048 16B chunks / 1024 threads)
    for (int g2 = tid; g2 < 2048; g2 += 1024) {
      int m = g2 >> 7, c = g2 & 127;
      uint4 v = *(const uint4*)(hr + ((r0 + m) << 10) + (c << 3));
      *(uint4*)(hs + m * 1032 + (c << 3)) = v;
    }
    __syncthreads();

    // partial gates over this wave's K chunk
    floatx4 acc = {0.f, 0.f, 0.f, 0.f};
#pragma unroll
    for (int s8 = 0; s8 < 8; s8++) {
      short8 af = *(const short8*)(hs + nloc * 1032 + kt * 256 + s8 * 32 + q * 8);
      acc = __builtin_amdgcn_mfma_f32_16x16x32_bf16(af, bfr[s8], acc, 0, 0, 0);
    }
    if (kt) {
#pragma unroll
      for (int r = 0; r < 4; r++) red[kt - 1][nt][q * 4 + r][nloc] = acc[r];
    }
    __syncthreads();

    if (kt == 0) {
      float gv[4];
#pragma unroll
      for (int r = 0; r < 4; r++)
        gv[r] = acc[r] + red[0][nt][q * 4 + r][nloc] + red[1][nt][q * 4 + r][nloc]
              + red[2][nt][q * 4 + r][nloc] + xv[r];
      const int sb = q << 4;
#pragma unroll
      for (int r = 0; r < 4; r++) {
        float vi = __shfl(gv[r], sb + u);
        float vf = __shfl(gv[r], sb + 4 + u);
        float vg = __shfl(gv[r], sb + 8 + u);
        float vo = __shfl(gv[r], sb + 12 + u);
        float i_ = sigf(vi), f_ = sigf(vf), g_ = tanhf_fast(vg), o_ = sigf(vo);
        float cn = f_ * cst[r] + i_ * g_;
        cst[r] = cn;
        float hn = o_ * tanhf_fast(cn);
        if (tg == 0) {
          int brow = r0 + (q << 2) + r;
          hw[(brow << 10) + j] = bf16_rne(hn);
          out_hid[(size_t)brow * (S_ * H_) + (size_t)t * H_ + j] = hn;
          if (t == 511) { out_h[(brow << 10) + j] = hn; out_c[(brow << 10) + j] = cn; }
        }
      }
      __builtin_amdgcn_fence(__ATOMIC_RELEASE, "agent");  // publish h slice
    }
    __syncthreads();

    if (t < 511) {
      // single-phase monotonic barrier
      if (tid == 0) {
        atomicAdd(cnt, 1u);
        const unsigned target = (unsigned)NBLK * (unsigned)(t + 1);
        while (__hip_atomic_load(cnt, __ATOMIC_RELAXED, __HIP_MEMORY_SCOPE_AGENT) < target)
          __builtin_amdgcn_s_sleep(1);
      }
      __syncthreads();
      __builtin_amdgcn_fence(__ATOMIC_ACQUIRE, "agent"); // invalidate before reading h
    }
  }
}

// ---------------- host ----------------
extern "C" void kernel_launch(void* const* d_in, const int* in_sizes, int n_in,
                              void* d_out, int out_size, void* d_ws, size_t ws_size,
                              hipStream_t stream) {
  const float* x  = (const float*)d_in[0];
  const float* h0 = (const float*)d_in[1];
  const float* c0 = (const float*)d_in[2];
  const float* Wi = (const float*)d_in[3];
  const float* bi = (const float*)d_in[4];
  const float* Wh = (const float*)d_in[5];
  const float* bh = (const float*)d_in[6];

  float* out_hid = (float*)d_out;
  float* out_h = out_hid + (size_t)B_ * S_ * H_;
  float* out_c = out_h + (size_t)B_ * H_;

  uint8_t* ws = (uint8_t*)d_ws;
  const size_t xg_fp32 = (size_t)S_ * B_ * G_ * 4;   // 512 MB
  const size_t xg_bf16 = (size_t)S_ * B_ * G_ * 2;   // 256 MB
  const size_t xbf_b = (size_t)B_ * S_ * D_ * 2;     // 64 MB
  const size_t w_b = (size_t)G_ * D_ * 2;            // 8 MB each
  const size_t rest = xbf_b + 2 * w_b + (size_t)G_ * 4 + (size_t)2 * B_ * H_ * 2 + 256;
  int xg16 = (ws_size >= xg_fp32 + rest) ? 0 : 1;
  size_t xg_bytes = xg16 ? xg_bf16 : xg_fp32;

  size_t off = 0;
  void* xg = (void*)(ws + off);                      off += xg_bytes;
  unsigned short* xbf = (unsigned short*)(ws + off); off += xbf_b;
  unsigned short* wib = (unsigned short*)(ws + off); off += w_b;
  unsigned short* whb = (unsigned short*)(ws + off); off += w_b;
  float* bsum = (float*)(ws + off);                  off += (size_t)G_ * 4;
  unsigned short* hb = (unsigned short*)(ws + off);  off += (size_t)2 * B_ * H_ * 2;
  unsigned* cnt = (unsigned*)(ws + off);

  hipMemsetAsync(cnt, 0, 256, stream);
  f32_to_bf16_k<<<(B_ * S_ * D_ / 4 + 255) / 256, 256, 0, stream>>>(x, xbf, B_ * S_ * D_);
  f32_to_bf16_k<<<(G_ * D_ / 4 + 255) / 256, 256, 0, stream>>>(Wi, wib, G_ * D_);
  f32_to_bf16_k<<<(G_ * D_ / 4 + 255) / 256, 256, 0, stream>>>(Wh, whb, G_ * D_);
  bsum_k<<<G_ / 256, 256, 0, stream>>>(bi, bh, bsum);
  hinit_k<<<(B_ * H_ + 255) / 256, 256, 0, stream>>>(h0, hb);

  gemm_xg<<<dim3((S_ * B_ / 128) * (G_ / 128)), 256, 0, stream>>>(xbf, wib, bsum, xg, xg16);

  void* args[] = { (void*)&xg, (void*)&xg16, (void*)&whb, (void*)&hb, (void*)&c0,
                   (void*)&out_hid, (void*)&out_h, (void*)&out_c, (void*)&cnt };
  hipLaunchCooperativeKernel((void*)lstm_rec, dim3(NBLK), dim3(1024), args, 0, stream);
}

// Round 2
// 6640.524 us; speedup vs baseline: 4.0996x; 4.0996x over previous
//
#include <hip/hip_runtime.h>
#include <cstdint>
#include <cstddef>

#define B_ 64
#define S_ 512
#define D_ 1024
#define H_ 1024
#define G_ 4096       // 4*H
#define NBLK 256      // cooperative grid for recurrence

typedef short short8 __attribute__((ext_vector_type(8)));
typedef float floatx4 __attribute__((ext_vector_type(4)));

__device__ __forceinline__ unsigned short bf16_rne(float f) {
  union { float f; unsigned u; } v; v.f = f;
  return (unsigned short)((v.u + 0x7FFFu + ((v.u >> 16) & 1u)) >> 16);
}
__device__ __forceinline__ float sigf(float x) { return 1.0f / (1.0f + __expf(-x)); }
__device__ __forceinline__ float tanhf_fast(float x) {
  float e = __expf(2.0f * x);
  return 1.0f - 2.0f / (e + 1.0f);   // safe at +-inf (no NaN)
}

// agent-scope per-access coherent ops (sc0|sc1 cache-bypass, NO wbl2/inv tag walks)
__device__ __forceinline__ uint64_t aload64(const void* p) {
  return __hip_atomic_load((const unsigned long long*)p, __ATOMIC_RELAXED, __HIP_MEMORY_SCOPE_AGENT);
}
__device__ __forceinline__ void astore64(void* p, uint64_t v) {
  __hip_atomic_store((unsigned long long*)p, (unsigned long long)v,
                     __ATOMIC_RELAXED, __HIP_MEMORY_SCOPE_AGENT);
}
__device__ __forceinline__ unsigned aload32(const unsigned* p) {
  return __hip_atomic_load(p, __ATOMIC_RELAXED, __HIP_MEMORY_SCOPE_AGENT);
}

// ---------------- prep kernels ----------------
__global__ void f32_to_bf16_k(const float* __restrict__ s, unsigned short* __restrict__ d, int n) {
  int i = (blockIdx.x * 256 + threadIdx.x) * 4;
  if (i < n) {
    float4 v = *(const float4*)(s + i);
    ushort4 o;
    o.x = bf16_rne(v.x); o.y = bf16_rne(v.y); o.z = bf16_rne(v.z); o.w = bf16_rne(v.w);
    *(ushort4*)(d + i) = o;
  }
}

__global__ void bsum_k(const float* __restrict__ bi, const float* __restrict__ bh, float* __restrict__ o) {
  int i = blockIdx.x * 256 + threadIdx.x;
  if (i < G_) o[i] = bi[i] + bh[i];
}

__global__ void hinit_k(const float* __restrict__ h0, unsigned short* __restrict__ hb) {
  int i = blockIdx.x * 256 + threadIdx.x;   // 0..65535
  if (i < B_ * H_) hb[i] = bf16_rne(h0[i & (H_ - 1)]);
}

// ---------------- phase 1: xg = x @ Wi^T + (bi+bh) ----------------
// 128x128 tile, BK=64, 4 waves each computing 64x64 via 4x4 16x16x32 MFMAs.
__global__ __launch_bounds__(256, 3) void gemm_xg(
    const unsigned short* __restrict__ xa,   // [32768][1024] bf16 (token-major: b*512+s)
    const unsigned short* __restrict__ wb,   // [4096][1024] bf16
    const float* __restrict__ bsum,          // [4096]
    void* __restrict__ xgv, int xg16)        // out: [512][64][4096]
{
  __shared__ unsigned short As[128 * 72];    // pad 64->72 elems to break bank conflicts
  __shared__ unsigned short Bs[128 * 72];
  const int tid = threadIdx.x, ln = tid & 63, wv = tid >> 6;
  const int q = ln >> 4, lr = ln & 15;
  const int bid = blockIdx.x;
  const int nt = bid & 31, mt = bid >> 5;
  const int m0 = mt << 7, n0 = nt << 7;
  const int wm = (wv & 1) << 6, wn = (wv >> 1) << 6;
  floatx4 acc[4][4] = {};

  for (int kk = 0; kk < 1024; kk += 64) {
    __syncthreads();
#pragma unroll
    for (int i = 0; i < 4; i++) {
      int f = i * 256 + tid;                 // 1024 chunks of 8 elems
      int row = f >> 3, c8 = (f & 7) << 3;
      short8 va = *(const short8*)(xa + (size_t)(m0 + row) * 1024 + kk + c8);
      short8 vb = *(const short8*)(wb + (size_t)(n0 + row) * 1024 + kk + c8);
      *(short8*)(As + row * 72 + c8) = va;
      *(short8*)(Bs + row * 72 + c8) = vb;
    }
    __syncthreads();
#pragma unroll
    for (int ks = 0; ks < 2; ks++) {
      short8 af[4], bf[4];
#pragma unroll
      for (int mi = 0; mi < 4; mi++)
        af[mi] = *(const short8*)(As + (wm + mi * 16 + lr) * 72 + ks * 32 + q * 8);
#pragma unroll
      for (int ni = 0; ni < 4; ni++)
        bf[ni] = *(const short8*)(Bs + (wn + ni * 16 + lr) * 72 + ks * 32 + q * 8);
#pragma unroll
      for (int mi = 0; mi < 4; mi++)
#pragma unroll
        for (int ni = 0; ni < 4; ni++)
          acc[mi][ni] = __builtin_amdgcn_mfma_f32_16x16x32_bf16(af[mi], bf[ni], acc[mi][ni], 0, 0, 0);
    }
  }
  // epilogue: D row = q*4+reg, col = lr ; write xg[s][b][n]
  const int b = m0 >> 9, s0 = m0 & 511;
#pragma unroll
  for (int mi = 0; mi < 4; mi++) {
#pragma unroll
    for (int r = 0; r < 4; r++) {
      int mrow = wm + mi * 16 + q * 4 + r;
      size_t base = (size_t)(s0 + mrow) * (B_ * G_) + (size_t)b * G_;
#pragma unroll
      for (int ni = 0; ni < 4; ni++) {
        int n = n0 + wn + ni * 16 + lr;
        float v = acc[mi][ni][r] + bsum[n];
        if (xg16) ((unsigned short*)xgv)[base + n] = bf16_rne(v);
        else      ((float*)xgv)[base + n] = v;
      }
    }
  }
}

// ---------------- phase 2: persistent cooperative recurrence ----------------
// 256 blocks = 4 batch-groups x 64 col-groups. Block owns 16 batch rows x 16 h-cols.
// 16 waves: wave = (nt in 0..3 [4 h-cols each], kt in 0..3 [K chunk of 256]).
// Wh fragments live in registers for the whole kernel. c state in fp32 registers.
// Cross-block h exchange: per-access agent atomics (sc0|sc1) -> Infinity Cache.
// NO agent fences (gfx950 lowers them to buffer_wbl2/buffer_inv L2 tag walks = ~50us each).
__global__ __launch_bounds__(1024, 1) void lstm_rec(
    const void* __restrict__ xgv, int xg16,  // [512][64][4096] (biases folded in)
    const unsigned short* __restrict__ wh,   // [4096][1024] bf16
    unsigned short* __restrict__ hb,         // [2][64][1024] bf16 (double buffer)
    const float* __restrict__ c0,            // [1024]
    float* __restrict__ out_hid,             // [64][512][1024]
    float* __restrict__ out_h,               // [64][1024]
    float* __restrict__ out_c,               // [64][1024]
    unsigned* __restrict__ cnt)              // 8 group counters, 64B apart
{
  __shared__ unsigned short hs[16 * 1032];   // h tile, padded rows (+8 elems)
  __shared__ float red[3][4][16][16];        // K-split partials [kt-1][nt][m][n]
  __shared__ unsigned short hout_bf[256];    // 16x16 h tile bf16 (for coalesced publish)
  __shared__ float hout_f[256];              // 16x16 h tile fp32 (for out_hid rows)

  const int tid = threadIdx.x, ln = tid & 63, wv = tid >> 6;
  const int nt = wv & 3, kt = wv >> 2;
  const int bid = blockIdx.x, bg = bid & 3, cg = bid >> 2;
  const int r0 = bg << 4, j0 = cg << 4;
  const int nloc = ln & 15, q = ln >> 4;
  const int tg = nloc >> 2, u = nloc & 3;    // gate type / h-col within group
  const int j = j0 + (nt << 2) + u;          // this lane's h column
  const int gcol = tg * 1024 + j;            // this lane's Wh row (gate column)

  // load Wh fragments once: lane holds Wh[gcol][kt*256 + s8*32 + q*8 .. +8]
  short8 bfr[8];
#pragma unroll
  for (int s8 = 0; s8 < 8; s8++)
    bfr[s8] = *(const short8*)(wh + (size_t)gcol * 1024 + kt * 256 + s8 * 32 + q * 8);

  float cst[4];
#pragma unroll
  for (int r = 0; r < 4; r++) cst[r] = c0[j];  // broadcast over batch

  for (int t = 0; t < 512; t++) {
    const unsigned short* hr = hb + (t & 1) * (B_ * H_);
    unsigned short* hw = hb + ((t + 1) & 1) * (B_ * H_);

    // A: prefetch this step's xg values (plain cached loads; xg written in a prior dispatch)
    float xv[4] = {0.f, 0.f, 0.f, 0.f};
    if (kt == 0) {
      const size_t xbase = (size_t)t * (B_ * G_) + (size_t)r0 * G_ + gcol;
      if (xg16) {
#pragma unroll
        for (int r = 0; r < 4; r++) {
          unsigned short w = ((const unsigned short*)xgv)[xbase + (size_t)(q * 4 + r) * G_];
          union { unsigned uu; float ff; } cv; cv.uu = ((unsigned)w) << 16; xv[r] = cv.ff;
        }
      } else {
#pragma unroll
        for (int r = 0; r < 4; r++)
          xv[r] = ((const float*)xgv)[xbase + (size_t)(q * 4 + r) * G_];
      }
    }

    // B: stage h tile 16x1024 bf16 -> LDS via 8B agent loads (bypass L1/L2, hit L3)
#pragma unroll
    for (int it = 0; it < 4; it++) {
      int g2 = it * 1024 + tid;              // 4096 8B chunks
      int m = g2 >> 8, c8 = g2 & 255;        // row (256 chunks of 8B per 2KB row)
      uint64_t v = aload64(hr + ((r0 + m) << 10) + (c8 << 2));
      *(uint64_t*)(hs + m * 1032 + (c8 << 2)) = v;
    }
    __syncthreads();   // S1: hs ready

    // C: partial gates over this wave's K chunk
    floatx4 acc = {0.f, 0.f, 0.f, 0.f};
#pragma unroll
    for (int s8 = 0; s8 < 8; s8++) {
      short8 af = *(const short8*)(hs + nloc * 1032 + kt * 256 + s8 * 32 + q * 8);
      acc = __builtin_amdgcn_mfma_f32_16x16x32_bf16(af, bfr[s8], acc, 0, 0, 0);
    }
    if (kt) {
#pragma unroll
      for (int r = 0; r < 4; r++) red[kt - 1][nt][q * 4 + r][nloc] = acc[r];
    }
    __syncthreads();   // S2: red ready

    // D: epilogue (kt==0 waves): reduce, pointwise, stash h tile in LDS
    if (kt == 0) {
      float gv[4];
#pragma unroll
      for (int r = 0; r < 4; r++)
        gv[r] = acc[r] + red[0][nt][q * 4 + r][nloc] + red[1][nt][q * 4 + r][nloc]
              + red[2][nt][q * 4 + r][nloc] + xv[r];
      const int sb = q << 4;
#pragma unroll
      for (int r = 0; r < 4; r++) {
        float vi = __shfl(gv[r], sb + u);
        float vf = __shfl(gv[r], sb + 4 + u);
        float vg = __shfl(gv[r], sb + 8 + u);
        float vo = __shfl(gv[r], sb + 12 + u);
        float i_ = sigf(vi), f_ = sigf(vf), g_ = tanhf_fast(vg), o_ = sigf(vo);
        float cn = f_ * cst[r] + i_ * g_;
        cst[r] = cn;
        float hn = o_ * tanhf_fast(cn);
        if (tg == 0) {
          int m = (q << 2) + r;              // local batch row
          hout_bf[(m << 4) + (nt << 2) + u] = bf16_rne(hn);
          hout_f [(m << 4) + (nt << 2) + u] = hn;
          if (t == 511) {
            int brow = r0 + m;
            out_h[(brow << 10) + j] = hn;
            out_c[(brow << 10) + j] = cn;
          }
        }
      }
    }
    __syncthreads();   // S3: hout ready

    // E+F: wave 0 publishes h (8B agent stores -> L3) + out_hid rows, then barrier
    if (wv == 0) {
      int row = ln >> 2, c4 = (ln & 3) << 2;
      uint64_t hv = *(const uint64_t*)(hout_bf + (row << 4) + c4);
      float4 fv = *(const float4*)(hout_f + (row << 4) + c4);
      astore64(hw + ((r0 + row) << 10) + j0 + c4, hv);
      *(float4*)(out_hid + (size_t)(r0 + row) * (S_ * H_) + (size_t)t * H_ + j0 + c4) = fv;
      __asm__ volatile("" ::: "memory");
      __builtin_amdgcn_s_waitcnt(0);         // h stores visible at coherence point
      __asm__ volatile("" ::: "memory");
      if (t < 511 && ln == 0) {
        atomicAdd(cnt + ((bid & 7) << 4), 1u);   // 8 groups of 32 -> low RMW contention
        const unsigned target = (unsigned)(t + 1) << 5;
        for (;;) {
          unsigned mn = 0xffffffffu;
#pragma unroll
          for (int gix = 0; gix < 8; gix++) {
            unsigned v = aload32(cnt + (gix << 4));
            mn = v < mn ? v : mn;
          }
          if (mn >= target) break;
          __builtin_amdgcn_s_sleep(1);
        }
      }
    }
    __syncthreads();   // S4: all blocks' h published; safe to read hb[(t+1)&1]
  }
}

// ---------------- host ----------------
extern "C" void kernel_launch(void* const* d_in, const int* in_sizes, int n_in,
                              void* d_out, int out_size, void* d_ws, size_t ws_size,
                              hipStream_t stream) {
  const float* x  = (const float*)d_in[0];
  const float* h0 = (const float*)d_in[1];
  const float* c0 = (const float*)d_in[2];
  const float* Wi = (const float*)d_in[3];
  const float* bi = (const float*)d_in[4];
  const float* Wh = (const float*)d_in[5];
  const float* bh = (const float*)d_in[6];

  float* out_hid = (float*)d_out;
  float* out_h = out_hid + (size_t)B_ * S_ * H_;
  float* out_c = out_h + (size_t)B_ * H_;

  uint8_t* ws = (uint8_t*)d_ws;
  const size_t xg_fp32 = (size_t)S_ * B_ * G_ * 4;   // 512 MB
  const size_t xg_bf16 = (size_t)S_ * B_ * G_ * 2;   // 256 MB
  const size_t xbf_b = (size_t)B_ * S_ * D_ * 2;     // 64 MB
  const size_t w_b = (size_t)G_ * D_ * 2;            // 8 MB each
  const size_t rest = xbf_b + 2 * w_b + (size_t)G_ * 4 + (size_t)2 * B_ * H_ * 2 + 2048;
  int xg16 = (ws_size >= xg_fp32 + rest) ? 0 : 1;
  size_t xg_bytes = xg16 ? xg_bf16 : xg_fp32;

  size_t off = 0;
  void* xg = (void*)(ws + off);                      off += xg_bytes;
  unsigned short* xbf = (unsigned short*)(ws + off); off += xbf_b;
  unsigned short* wib = (unsigned short*)(ws + off); off += w_b;
  unsigned short* whb = (unsigned short*)(ws + off); off += w_b;
  float* bsum = (float*)(ws + off);                  off += (size_t)G_ * 4;
  unsigned short* hb = (unsigned short*)(ws + off);  off += (size_t)2 * B_ * H_ * 2;
  off = (off + 255) & ~(size_t)255;
  unsigned* cnt = (unsigned*)(ws + off);

  hipMemsetAsync(cnt, 0, 1024, stream);
  f32_to_bf16_k<<<(B_ * S_ * D_ / 4 + 255) / 256, 256, 0, stream>>>(x, xbf, B_ * S_ * D_);
  f32_to_bf16_k<<<(G_ * D_ / 4 + 255) / 256, 256, 0, stream>>>(Wi, wib, G_ * D_);
  f32_to_bf16_k<<<(G_ * D_ / 4 + 255) / 256, 256, 0, stream>>>(Wh, whb, G_ * D_);
  bsum_k<<<G_ / 256, 256, 0, stream>>>(bi, bh, bsum);
  hinit_k<<<(B_ * H_ + 255) / 256, 256, 0, stream>>>(h0, hb);

  gemm_xg<<<dim3((S_ * B_ / 128) * (G_ / 128)), 256, 0, stream>>>(xbf, wib, bsum, xg, xg16);

  void* args[] = { (void*)&xg, (void*)&xg16, (void*)&whb, (void*)&hb, (void*)&c0,
                   (void*)&out_hid, (void*)&out_h, (void*)&out_c, (void*)&cnt };
  hipLaunchCooperativeKernel((void*)lstm_rec, dim3(NBLK), dim3(1024), args, 0, stream);
}

// Round 3
// 3109.327 us; speedup vs baseline: 8.7553x; 2.1357x over previous
//
#include <hip/hip_runtime.h>
#include <cstdint>
#include <cstddef>

#define B_ 64
#define S_ 512
#define D_ 1024
#define H_ 1024
#define G_ 4096       // 4*H
#define NBLK 256      // cooperative grid for recurrence

typedef short short8 __attribute__((ext_vector_type(8)));
typedef float floatx4 __attribute__((ext_vector_type(4)));

__device__ __forceinline__ unsigned short bf16_rne(float f) {
  union { float f; unsigned u; } v; v.f = f;
  return (unsigned short)((v.u + 0x7FFFu + ((v.u >> 16) & 1u)) >> 16);
}
__device__ __forceinline__ float sigf(float x) { return 1.0f / (1.0f + __expf(-x)); }
__device__ __forceinline__ float tanhf_fast(float x) {
  float e = __expf(2.0f * x);
  return 1.0f - 2.0f / (e + 1.0f);   // safe at +-inf (no NaN)
}

// agent-scope per-access coherent ops (sc0|sc1 cache-bypass, NO wbl2/inv tag walks)
__device__ __forceinline__ void astore64(void* p, uint64_t v) {
  __hip_atomic_store((unsigned long long*)p, (unsigned long long)v,
                     __ATOMIC_RELAXED, __HIP_MEMORY_SCOPE_AGENT);
}
__device__ __forceinline__ void astore32(unsigned* p, unsigned v) {
  __hip_atomic_store(p, v, __ATOMIC_RELAXED, __HIP_MEMORY_SCOPE_AGENT);
}
__device__ __forceinline__ unsigned aload32(const unsigned* p) {
  return __hip_atomic_load(p, __ATOMIC_RELAXED, __HIP_MEMORY_SCOPE_AGENT);
}
// two coherent 16B loads, one wait (L1/L2-bypass via sc0|sc1)
__device__ __forceinline__ void cload2x128(uint4* d0, uint4* d1, const void* p0, const void* p1) {
  asm volatile("global_load_dwordx4 %0, %2, off sc0 sc1\n\t"
               "global_load_dwordx4 %1, %3, off sc0 sc1\n\t"
               "s_waitcnt vmcnt(0)"
               : "=&v"(*d0), "=&v"(*d1)
               : "v"(p0), "v"(p1)
               : "memory");
}

// ---------------- prep kernels ----------------
__global__ void f32_to_bf16_k(const float* __restrict__ s, unsigned short* __restrict__ d, int n) {
  int i = (blockIdx.x * 256 + threadIdx.x) * 4;
  if (i < n) {
    float4 v = *(const float4*)(s + i);
    ushort4 o;
    o.x = bf16_rne(v.x); o.y = bf16_rne(v.y); o.z = bf16_rne(v.z); o.w = bf16_rne(v.w);
    *(ushort4*)(d + i) = o;
  }
}

__global__ void bsum_k(const float* __restrict__ bi, const float* __restrict__ bh, float* __restrict__ o) {
  int i = blockIdx.x * 256 + threadIdx.x;
  if (i < G_) o[i] = bi[i] + bh[i];
}

__global__ void hinit_k(const float* __restrict__ h0, unsigned short* __restrict__ hb) {
  int i = blockIdx.x * 256 + threadIdx.x;   // 0..65535
  if (i < B_ * H_) hb[i] = bf16_rne(h0[i & (H_ - 1)]);
}

// ---------------- phase 1: xg = x @ Wi^T + (bi+bh) ----------------
__global__ __launch_bounds__(256, 3) void gemm_xg(
    const unsigned short* __restrict__ xa,   // [32768][1024] bf16 (token-major: b*512+s)
    const unsigned short* __restrict__ wb,   // [4096][1024] bf16
    const float* __restrict__ bsum,          // [4096]
    void* __restrict__ xgv, int xg16)        // out: [512][64][4096]
{
  __shared__ unsigned short As[128 * 72];
  __shared__ unsigned short Bs[128 * 72];
  const int tid = threadIdx.x, ln = tid & 63, wv = tid >> 6;
  const int q = ln >> 4, lr = ln & 15;
  const int bid = blockIdx.x;
  const int nt = bid & 31, mt = bid >> 5;
  const int m0 = mt << 7, n0 = nt << 7;
  const int wm = (wv & 1) << 6, wn = (wv >> 1) << 6;
  floatx4 acc[4][4] = {};

  for (int kk = 0; kk < 1024; kk += 64) {
    __syncthreads();
#pragma unroll
    for (int i = 0; i < 4; i++) {
      int f = i * 256 + tid;
      int row = f >> 3, c8 = (f & 7) << 3;
      short8 va = *(const short8*)(xa + (size_t)(m0 + row) * 1024 + kk + c8);
      short8 vb = *(const short8*)(wb + (size_t)(n0 + row) * 1024 + kk + c8);
      *(short8*)(As + row * 72 + c8) = va;
      *(short8*)(Bs + row * 72 + c8) = vb;
    }
    __syncthreads();
#pragma unroll
    for (int ks = 0; ks < 2; ks++) {
      short8 af[4], bf[4];
#pragma unroll
      for (int mi = 0; mi < 4; mi++)
        af[mi] = *(const short8*)(As + (wm + mi * 16 + lr) * 72 + ks * 32 + q * 8);
#pragma unroll
      for (int ni = 0; ni < 4; ni++)
        bf[ni] = *(const short8*)(Bs + (wn + ni * 16 + lr) * 72 + ks * 32 + q * 8);
#pragma unroll
      for (int mi = 0; mi < 4; mi++)
#pragma unroll
        for (int ni = 0; ni < 4; ni++)
          acc[mi][ni] = __builtin_amdgcn_mfma_f32_16x16x32_bf16(af[mi], bf[ni], acc[mi][ni], 0, 0, 0);
    }
  }
  const int b = m0 >> 9, s0 = m0 & 511;
#pragma unroll
  for (int mi = 0; mi < 4; mi++) {
#pragma unroll
    for (int r = 0; r < 4; r++) {
      int mrow = wm + mi * 16 + q * 4 + r;
      size_t base = (size_t)(s0 + mrow) * (B_ * G_) + (size_t)b * G_;
#pragma unroll
      for (int ni = 0; ni < 4; ni++) {
        int n = n0 + wn + ni * 16 + lr;
        float v = acc[mi][ni][r] + bsum[n];
        if (xg16) ((unsigned short*)xgv)[base + n] = bf16_rne(v);
        else      ((float*)xgv)[base + n] = v;
      }
    }
  }
}

// ---------------- phase 2: persistent cooperative recurrence ----------------
// 256 blocks = 4 batch-groups x 64 col-groups; per-bg independent flag-tree barrier.
// No atomics: arrival slots (plain agent stores) + per-bg aggregator wave + replicated flags.
__global__ __launch_bounds__(1024, 1) void lstm_rec(
    const void* __restrict__ xgv, int xg16,  // [512][64][4096] (biases folded in)
    const unsigned short* __restrict__ wh,   // [4096][1024] bf16
    unsigned short* __restrict__ hb,         // [2][64][1024] bf16 (double buffer)
    const float* __restrict__ c0,            // [1024]
    float* __restrict__ out_hid,             // [64][512][1024]
    float* __restrict__ out_h,               // [64][1024]
    float* __restrict__ out_c,               // [64][1024]
    unsigned* __restrict__ sync)             // arr[4][64] @0 ; flag[4][8 reps][16] @+256
{
  __shared__ unsigned short hs[16 * 1032];   // h tile, padded rows (+8 elems)
  __shared__ float red[3][4][16][16];        // K-split partials [kt-1][nt][m][n]
  __shared__ unsigned short hout_bf[256];    // 16x16 h tile bf16 (publish)
  __shared__ float hout_f[256];              // 16x16 h tile fp32 (out_hid)

  const int tid = threadIdx.x, ln = tid & 63, wv = tid >> 6;
  const int nt = wv & 3, kt = wv >> 2;
  const int bid = blockIdx.x, bg = bid & 3, cg = bid >> 2;
  const int r0 = bg << 4, j0 = cg << 4;
  const int nloc = ln & 15, q = ln >> 4;
  const int tg = nloc >> 2, u = nloc & 3;
  const int j = j0 + (nt << 2) + u;
  const int gcol = tg * 1024 + j;

  unsigned* arr_bg = sync + (bg << 6);            // 64 dwords
  unsigned* flag_bg = sync + 256 + (bg << 7);     // 8 reps x 16 dwords

  short8 bfr[8];
#pragma unroll
  for (int s8 = 0; s8 < 8; s8++)
    bfr[s8] = *(const short8*)(wh + (size_t)gcol * 1024 + kt * 256 + s8 * 32 + q * 8);

  float cst[4];
#pragma unroll
  for (int r = 0; r < 4; r++) cst[r] = c0[j];

  for (int t = 0; t < 512; t++) {
    const unsigned short* hr = hb + (t & 1) * (B_ * H_);
    unsigned short* hw = hb + ((t + 1) & 1) * (B_ * H_);

    // A: xg prefetch (plain cached loads; independent of h)
    float xv[4] = {0.f, 0.f, 0.f, 0.f};
    if (kt == 0) {
      const size_t xbase = (size_t)t * (B_ * G_) + (size_t)r0 * G_ + gcol;
      if (xg16) {
#pragma unroll
        for (int r = 0; r < 4; r++) {
          unsigned short w = ((const unsigned short*)xgv)[xbase + (size_t)(q * 4 + r) * G_];
          union { unsigned uu; float ff; } cv; cv.uu = ((unsigned)w) << 16; xv[r] = cv.ff;
        }
      } else {
#pragma unroll
        for (int r = 0; r < 4; r++)
          xv[r] = ((const float*)xgv)[xbase + (size_t)(q * 4 + r) * G_];
      }
    }

    // B: stage h tile 16x1024 bf16 -> LDS via two 16B coherent loads per thread
    {
      int g0 = tid, g1 = tid + 1024;           // 2048 16B chunks
      const void* p0 = hr + ((r0 + (g0 >> 7)) << 10) + ((g0 & 127) << 3);
      const void* p1 = hr + ((r0 + (g1 >> 7)) << 10) + ((g1 & 127) << 3);
      uint4 a, b;
      cload2x128(&a, &b, p0, p1);
      *(uint4*)(hs + (g0 >> 7) * 1032 + ((g0 & 127) << 3)) = a;
      *(uint4*)(hs + (g1 >> 7) * 1032 + ((g1 & 127) << 3)) = b;
    }
    __syncthreads();   // S1: hs ready

    // C: partial gates over this wave's K chunk
    floatx4 acc = {0.f, 0.f, 0.f, 0.f};
#pragma unroll
    for (int s8 = 0; s8 < 8; s8++) {
      short8 af = *(const short8*)(hs + nloc * 1032 + kt * 256 + s8 * 32 + q * 8);
      acc = __builtin_amdgcn_mfma_f32_16x16x32_bf16(af, bfr[s8], acc, 0, 0, 0);
    }
    if (kt) {
#pragma unroll
      for (int r = 0; r < 4; r++) red[kt - 1][nt][q * 4 + r][nloc] = acc[r];
    }
    __syncthreads();   // S2: red ready

    // D: epilogue (kt==0 waves)
    if (kt == 0) {
      float gv[4];
#pragma unroll
      for (int r = 0; r < 4; r++)
        gv[r] = acc[r] + red[0][nt][q * 4 + r][nloc] + red[1][nt][q * 4 + r][nloc]
              + red[2][nt][q * 4 + r][nloc] + xv[r];
      const int sb = q << 4;
#pragma unroll
      for (int r = 0; r < 4; r++) {
        float vi = __shfl(gv[r], sb + u);
        float vf = __shfl(gv[r], sb + 4 + u);
        float vg = __shfl(gv[r], sb + 8 + u);
        float vo = __shfl(gv[r], sb + 12 + u);
        float i_ = sigf(vi), f_ = sigf(vf), g_ = tanhf_fast(vg), o_ = sigf(vo);
        float cn = f_ * cst[r] + i_ * g_;
        cst[r] = cn;
        float hn = o_ * tanhf_fast(cn);
        if (tg == 0) {
          int m = (q << 2) + r;
          hout_bf[(m << 4) + (nt << 2) + u] = bf16_rne(hn);
          hout_f [(m << 4) + (nt << 2) + u] = hn;
          if (t == 511) {
            int brow = r0 + m;
            out_h[(brow << 10) + j] = hn;
            out_c[(brow << 10) + j] = cn;
          }
        }
      }
    }
    __syncthreads();   // S3: hout ready

    if (wv == 0) {
      // E: publish h (64 lanes x 8B agent stores -> L3)
      int row = ln >> 2, c4 = (ln & 3) << 2;
      uint64_t hv = *(const uint64_t*)(hout_bf + (row << 4) + c4);
      astore64(hw + ((r0 + row) << 10) + j0 + c4, hv);
      __asm__ volatile("" ::: "memory");
      __builtin_amdgcn_s_waitcnt(0);           // h acked at coherence point
      __asm__ volatile("" ::: "memory");
      if (t < 511) {
        if (ln == 0) astore32(arr_bg + cg, (unsigned)(t + 1));  // arrival (no RMW)
        const unsigned tgt = (unsigned)(t + 1);
        if (cg == 0) {
          // aggregator: whole wave polls 64 arrival slots, min-reduce, publish flags
          for (;;) {
            unsigned v = aload32(arr_bg + ln);
#pragma unroll
            for (int d = 32; d >= 1; d >>= 1) {
              unsigned o = __shfl_xor(v, d);
              v = v < o ? v : o;
            }
            if (v >= tgt) break;
            __builtin_amdgcn_s_sleep(2);
          }
          if (ln < 8) astore32(flag_bg + (ln << 4), tgt);
        } else if (ln == 0) {
          // peer: poll one replica line (<=8 pollers per line)
          const unsigned* fl = flag_bg + ((cg & 7) << 4);
          while (aload32(fl) < tgt) __builtin_amdgcn_s_sleep(8);
        }
      }
    } else if (wv == 1) {
      // F: out_hid rows (plain cached stores; drain overlaps next staging)
      int row = ln >> 2, c4 = (ln & 3) << 2;
      float4 fv = *(const float4*)(hout_f + (row << 4) + c4);
      *(float4*)(out_hid + (size_t)(r0 + row) * (S_ * H_) + (size_t)t * H_ + j0 + c4) = fv;
    }
    __syncthreads();   // S4: bg's h published & visible; safe to read hb[(t+1)&1]
  }
}

// ---------------- host ----------------
extern "C" void kernel_launch(void* const* d_in, const int* in_sizes, int n_in,
                              void* d_out, int out_size, void* d_ws, size_t ws_size,
                              hipStream_t stream) {
  const float* x  = (const float*)d_in[0];
  const float* h0 = (const float*)d_in[1];
  const float* c0 = (const float*)d_in[2];
  const float* Wi = (const float*)d_in[3];
  const float* bi = (const float*)d_in[4];
  const float* Wh = (const float*)d_in[5];
  const float* bh = (const float*)d_in[6];

  float* out_hid = (float*)d_out;
  float* out_h = out_hid + (size_t)B_ * S_ * H_;
  float* out_c = out_h + (size_t)B_ * H_;

  uint8_t* ws = (uint8_t*)d_ws;
  const size_t xg_fp32 = (size_t)S_ * B_ * G_ * 4;   // 512 MB
  const size_t xg_bf16 = (size_t)S_ * B_ * G_ * 2;   // 256 MB
  const size_t xbf_b = (size_t)B_ * S_ * D_ * 2;     // 64 MB
  const size_t w_b = (size_t)G_ * D_ * 2;            // 8 MB each
  const size_t rest = xbf_b + 2 * w_b + (size_t)G_ * 4 + (size_t)2 * B_ * H_ * 2 + 8192;
  int xg16 = (ws_size >= xg_fp32 + rest) ? 0 : 1;
  size_t xg_bytes = xg16 ? xg_bf16 : xg_fp32;

  size_t off = 0;
  void* xg = (void*)(ws + off);                      off += xg_bytes;
  unsigned short* xbf = (unsigned short*)(ws + off); off += xbf_b;
  unsigned short* wib = (unsigned short*)(ws + off); off += w_b;
  unsigned short* whb = (unsigned short*)(ws + off); off += w_b;
  float* bsum = (float*)(ws + off);                  off += (size_t)G_ * 4;
  unsigned short* hb = (unsigned short*)(ws + off);  off += (size_t)2 * B_ * H_ * 2;
  off = (off + 255) & ~(size_t)255;
  unsigned* syncp = (unsigned*)(ws + off);

  hipMemsetAsync(syncp, 0, 4096, stream);
  f32_to_bf16_k<<<(B_ * S_ * D_ / 4 + 255) / 256, 256, 0, stream>>>(x, xbf, B_ * S_ * D_);
  f32_to_bf16_k<<<(G_ * D_ / 4 + 255) / 256, 256, 0, stream>>>(Wi, wib, G_ * D_);
  f32_to_bf16_k<<<(G_ * D_ / 4 + 255) / 256, 256, 0, stream>>>(Wh, whb, G_ * D_);
  bsum_k<<<G_ / 256, 256, 0, stream>>>(bi, bh, bsum);
  hinit_k<<<(B_ * H_ + 255) / 256, 256, 0, stream>>>(h0, hb);

  gemm_xg<<<dim3((S_ * B_ / 128) * (G_ / 128)), 256, 0, stream>>>(xbf, wib, bsum, xg, xg16);

  void* args[] = { (void*)&xg, (void*)&xg16, (void*)&whb, (void*)&hb, (void*)&c0,
                   (void*)&out_hid, (void*)&out_h, (void*)&out_c, (void*)&syncp };
  hipLaunchCooperativeKernel((void*)lstm_rec, dim3(NBLK), dim3(1024), args, 0, stream);
}